// Round 7
// baseline (324.548 us; speedup 1.0000x reference)
//
#include <hip/hip_runtime.h>
#include <hip/hip_cooperative_groups.h>

namespace cg = cooperative_groups;

// SymbolicTraversal: out[b, n] = max(0, max_{e: type[e]==r_index[b], dst[e]==n} h[b, src[e]])
//
// R6: single cooperative kernel (phaseA: zero+filter+bucket, grid.sync, phaseB:
// LDS-resolve + store). Eliminates 2 inter-kernel drain/launch overheads (~20us).
// Storage: store[bkt][block] = 64B segment {count, <=15 records}; written by exactly
// one (block,bucket) pair -> no global atomics. Overflow: per-block ws list (rare),
// then atomicMax into pre-zeroed out + flag (ultra-rare), merged by phaseB.
// Record: ((dst & 8191) << 17) | src  (needs N <= 2^17, guarded).
// Fallback: R5 3-kernel chain if cooperative launch unavailable or shape unsupported.

typedef int v4i __attribute__((ext_vector_type(4)));

#define NB 512
#define TH 256
#define QCAP 15
#define CSHIFT 13
#define MAXNBKT 416
#define OVCAP 4096

__global__ __launch_bounds__(TH)
void fused_kernel(const int* __restrict__ edge_index,
                  const int* __restrict__ etype,
                  const int* __restrict__ r_index,
                  const float* __restrict__ h,
                  int* __restrict__ out,
                  unsigned int* __restrict__ flag,   // 1 line
                  unsigned int* __restrict__ ovcnt,  // NB lines (word stride 16)
                  uint2* __restrict__ ovrec,         // [NB][OVCAP]
                  unsigned int* __restrict__ store,  // [nbkt][NB][16]
                  int B, int N, int E, int nchunk, int nbkt, int out_n) {
    cg::grid_group grid = cg::this_grid();
    __shared__ int sbuf[8192];          // 32KB union: A queues / B slice
    __shared__ unsigned int extra[2];   // [0]=ovl (A), [1]=ovtot (B)

    const int t = threadIdx.x;
    const int bid = blockIdx.x;
    const int gt = bid * TH + t;

    // ---- A0: zero out + flag (base for ultra-rare direct-atomic fallback) ----
    {
        const int n4 = out_n >> 2;
        v4i z = {0, 0, 0, 0};
        for (int i = gt; i < n4; i += NB * TH)
            *(reinterpret_cast<v4i*>(out) + i) = z;
        for (int i = (n4 << 2) + gt; i < out_n; i += NB * TH) out[i] = 0;
        if (gt == 0) flag[0] = 0u;
    }
    grid.sync();

    // ---- A1: stream edges, filter, bucket ----
    unsigned int* smask = (unsigned int*)sbuf;                 // 64
    unsigned int* lcnt  = (unsigned int*)sbuf + 64;            // MAXNBKT
    unsigned int* lq    = (unsigned int*)sbuf + 64 + MAXNBKT;  // MAXNBKT*QCAP

    if (t < 64) {
        unsigned int m = 0;
        for (int b = 0; b < B; ++b)
            if (r_index[b] == t) m |= (1u << b);
        smask[t] = m;
    }
    for (int i = t; i < nbkt; i += TH) lcnt[i] = 0;
    if (t == 0) extra[0] = 0;
    __syncthreads();

    const int* __restrict__ src = edge_index;
    const int* __restrict__ dst = edge_index + E;
    const unsigned int cmask = (1u << CSHIFT) - 1u;
    const int nq = E >> 2;

    for (int q = gt; q < nq; q += NB * TH) {
        v4i tv = __builtin_nontemporal_load(reinterpret_cast<const v4i*>(etype) + q);
        v4i sv = __builtin_nontemporal_load(reinterpret_cast<const v4i*>(src) + q);
        v4i dv = __builtin_nontemporal_load(reinterpret_cast<const v4i*>(dst) + q);
        #pragma unroll
        for (int i = 0; i < 4; ++i) {
            unsigned int ty = (unsigned int)tv[i];
            unsigned int m = (ty < 64u) ? smask[ty] : 0u;
            if (!m) continue;
            unsigned int d = (unsigned int)dv[i];
            unsigned int s = (unsigned int)sv[i];
            unsigned int rec = ((d & cmask) << 17) | s;
            int cb = (int)(d >> CSHIFT);
            do {
                int b = __builtin_ctz(m); m &= m - 1;
                int bkt = b * nchunk + cb;
                unsigned int pos = atomicAdd(&lcnt[bkt], 1u);
                if (pos < QCAP) {
                    lq[bkt * QCAP + pos] = rec;
                } else {
                    unsigned int p2 = atomicAdd(&extra[0], 1u);
                    if (p2 < OVCAP) {
                        uint2 rr; rr.x = (d << 5) | (unsigned int)b; rr.y = s;
                        ovrec[(size_t)bid * OVCAP + p2] = rr;
                    } else {
                        float v = h[(size_t)b * N + s];
                        atomicMax(out + (size_t)b * N + d, __float_as_int(v));
                        atomicOr(flag, 1u);
                    }
                }
            } while (m);
        }
    }
    if (bid == 0) {  // tail edges (E % 4)
        for (int e = (nq << 2) + t; e < E; e += TH) {
            unsigned int ty = (unsigned int)etype[e];
            unsigned int m = (ty < 64u) ? smask[ty] : 0u;
            unsigned int d = (unsigned int)dst[e];
            unsigned int s = (unsigned int)src[e];
            unsigned int rec = ((d & cmask) << 17) | s;
            int cb = (int)(d >> CSHIFT);
            while (m) {
                int b = __builtin_ctz(m); m &= m - 1;
                int bkt = b * nchunk + cb;
                unsigned int pos = atomicAdd(&lcnt[bkt], 1u);
                if (pos < QCAP) {
                    lq[bkt * QCAP + pos] = rec;
                } else {
                    unsigned int p2 = atomicAdd(&extra[0], 1u);
                    if (p2 < OVCAP) {
                        uint2 rr; rr.x = (d << 5) | (unsigned int)b; rr.y = s;
                        ovrec[(size_t)bid * OVCAP + p2] = rr;
                    } else {
                        float v = h[(size_t)b * N + s];
                        atomicMax(out + (size_t)b * N + d, __float_as_int(v));
                        atomicOr(flag, 1u);
                    }
                }
            }
        }
    }
    __syncthreads();

    // ---- A2: flush — each bucket one full 64B line; write overflow count ----
    if (t == 0) {
        unsigned int c = extra[0];
        ovcnt[bid * 16] = c > OVCAP ? OVCAP : c;
    }
    {
        const int wid = t >> 6, lane = t & 63;
        const int sub = lane >> 4, word = lane & 15;
        for (int k0 = wid * 4; k0 < nbkt; k0 += (TH / 64) * 4) {
            int k = k0 + sub;
            if (k < nbkt) {
                unsigned int n = lcnt[k]; if (n > QCAP) n = QCAP;
                unsigned int val = (word == 0) ? n : lq[k * QCAP + (word - 1)];
                store[((size_t)k * NB + bid) * 16 + word] = val;
            }
        }
    }
    grid.sync();

    // ---- B: resolve bucket in LDS, apply overflow, store ----
    if (bid < nbkt) {
        const int k = bid;
        const int b = k / nchunk;
        const int c = k % nchunk;
        const int csz = 1 << CSHIFT;
        int* slice = sbuf;

        for (int i = t; i < csz; i += TH) slice[i] = 0;
        if (t == 0) extra[1] = 0;
        __syncthreads();

        unsigned int myov = 0;
        for (int r = t; r < NB; r += TH) myov += ovcnt[r * 16];
        if (myov) atomicAdd(&extra[1], myov);

        const unsigned int* __restrict__ base = store + (size_t)k * NB * 16;
        const float* __restrict__ hb = h + (size_t)b * N;
        for (int r = t; r < NB; r += TH) {
            const unsigned int* __restrict__ seg = base + (size_t)r * 16;
            unsigned int n = seg[0]; if (n > QCAP) n = QCAP;
            for (unsigned int i = 1; i <= n; ++i) {
                unsigned int rec = seg[i];
                int s  = (int)(rec & 0x1FFFFu);
                int ld = (int)(rec >> 17);
                atomicMax(&slice[ld], __float_as_int(hb[s]));
            }
        }
        __syncthreads();

        if (extra[1] > 0) {  // rare level-2 overflow apply
            for (int r = 0; r < NB; ++r) {
                unsigned int cnt = ovcnt[r * 16];
                if (!cnt) continue;
                if (cnt > OVCAP) cnt = OVCAP;
                const uint2* __restrict__ rp = ovrec + (size_t)r * OVCAP;
                for (unsigned int i = t; i < cnt; i += TH) {
                    uint2 rr = rp[i];
                    int bb = (int)(rr.x & 31u);
                    unsigned int d = rr.x >> 5;
                    if (bb == b && (int)(d >> CSHIFT) == c)
                        atomicMax(&slice[d & cmask], __float_as_int(hb[rr.y]));
                }
            }
            __syncthreads();
        }

        const int d0 = c << CSHIFT;
        int cnt = N - d0; if (cnt > csz) cnt = csz;
        int* __restrict__ ob = out + (size_t)b * N + d0;
        const bool l3 = (flag[0] != 0u);
        for (int i = t; i < cnt; i += TH) {
            int v = slice[i];
            if (l3) { int cur = ob[i]; ob[i] = cur > v ? cur : v; }
            else ob[i] = v;
        }
    }
}

// ================= R5 fallback chain (proven 39us) =================

__global__ __launch_bounds__(256)
void zero_out_kernel(int* __restrict__ out, int n) {
    int i = (blockIdx.x * 256 + threadIdx.x) * 4;
    if (i + 3 < n) {
        v4i z = {0, 0, 0, 0};
        *reinterpret_cast<v4i*>(out + i) = z;
    } else {
        for (int j = i; j < n && j >= 0; ++j) out[j] = 0;
    }
}

__global__ __launch_bounds__(512)
void phase1_kernel(const int* __restrict__ edge_index,
                   const int* __restrict__ etype,
                   const int* __restrict__ r_index,
                   const float* __restrict__ h,
                   int* __restrict__ out,
                   unsigned int* __restrict__ store,   // [nbkt][512][16]
                   int B, int N, int E, int nchunk, int nbkt) {
    __shared__ unsigned int smask[64];
    __shared__ unsigned int lcnt[MAXNBKT];
    __shared__ unsigned int lq[MAXNBKT * QCAP];
    const int t = threadIdx.x;
    if (t < 64) {
        unsigned int m = 0;
        for (int b = 0; b < B; ++b)
            if (r_index[b] == t) m |= (1u << b);
        smask[t] = m;
    }
    for (int i = t; i < nbkt; i += 512) lcnt[i] = 0;
    __syncthreads();
    const int* __restrict__ src = edge_index;
    const int* __restrict__ dst = edge_index + E;
    const unsigned int cmask = (1u << CSHIFT) - 1u;
    const int nq = E >> 2;
    for (int q = blockIdx.x * 512 + t; q < nq; q += 512 * 512) {
        v4i tv = __builtin_nontemporal_load(reinterpret_cast<const v4i*>(etype) + q);
        v4i sv = __builtin_nontemporal_load(reinterpret_cast<const v4i*>(src) + q);
        v4i dv = __builtin_nontemporal_load(reinterpret_cast<const v4i*>(dst) + q);
        #pragma unroll
        for (int i = 0; i < 4; ++i) {
            unsigned int ty = (unsigned int)tv[i];
            unsigned int m = (ty < 64u) ? smask[ty] : 0u;
            if (!m) continue;
            unsigned int d = (unsigned int)dv[i];
            unsigned int s = (unsigned int)sv[i];
            unsigned int rec = ((d & cmask) << 17) | s;
            int cb = (int)(d >> CSHIFT);
            do {
                int b = __builtin_ctz(m); m &= m - 1;
                int bkt = b * nchunk + cb;
                unsigned int pos = atomicAdd(&lcnt[bkt], 1u);
                if (pos < QCAP) lq[bkt * QCAP + pos] = rec;
                else {
                    float v = h[(size_t)b * N + s];
                    atomicMax(out + (size_t)b * N + d, __float_as_int(v));
                }
            } while (m);
        }
    }
    if (blockIdx.x == 0) {
        for (int e = (nq << 2) + t; e < E; e += 512) {
            unsigned int ty = (unsigned int)etype[e];
            unsigned int m = (ty < 64u) ? smask[ty] : 0u;
            unsigned int d = (unsigned int)dst[e];
            unsigned int s = (unsigned int)src[e];
            unsigned int rec = ((d & cmask) << 17) | s;
            int cb = (int)(d >> CSHIFT);
            while (m) {
                int b = __builtin_ctz(m); m &= m - 1;
                int bkt = b * nchunk + cb;
                unsigned int pos = atomicAdd(&lcnt[bkt], 1u);
                if (pos < QCAP) lq[bkt * QCAP + pos] = rec;
                else {
                    float v = h[(size_t)b * N + s];
                    atomicMax(out + (size_t)b * N + d, __float_as_int(v));
                }
            }
        }
    }
    __syncthreads();
    const int wid = t >> 6, lane = t & 63;
    const int sub = lane >> 4, word = lane & 15;
    for (int k0 = wid * 4; k0 < nbkt; k0 += (512 / 64) * 4) {
        int k = k0 + sub;
        if (k < nbkt) {
            unsigned int n = lcnt[k]; if (n > QCAP) n = QCAP;
            unsigned int val = (word == 0) ? n : lq[k * QCAP + (word - 1)];
            store[((size_t)k * 512 + blockIdx.x) * 16 + word] = val;
        }
    }
}

__global__ __launch_bounds__(512)
void phase2_kernel(const float* __restrict__ h,
                   const unsigned int* __restrict__ store,
                   int N, int nchunk,
                   int* __restrict__ out) {
    __shared__ int slice[1 << CSHIFT];
    const int t = threadIdx.x;
    const int k = blockIdx.x;
    const int b = k / nchunk;
    const int c = k % nchunk;
    const int csz = 1 << CSHIFT;
    for (int i = t; i < csz; i += 512) slice[i] = 0;
    __syncthreads();
    const unsigned int* __restrict__ base = store + (size_t)k * 512 * 16;
    const float* __restrict__ hb = h + (size_t)b * N;
    for (int r = t; r < 512; r += 512) {
        const unsigned int* __restrict__ seg = base + (size_t)r * 16;
        unsigned int n = seg[0]; if (n > QCAP) n = QCAP;
        for (unsigned int i = 1; i <= n; ++i) {
            unsigned int rec = seg[i];
            int s  = (int)(rec & 0x1FFFFu);
            int ld = (int)(rec >> 17);
            atomicMax(&slice[ld], __float_as_int(hb[s]));
        }
    }
    __syncthreads();
    const int d0 = c << CSHIFT;
    int cnt = N - d0; if (cnt > csz) cnt = csz;
    int* __restrict__ ob = out + (size_t)b * N + d0;
    for (int i = t; i < cnt; i += 512) {
        int cur = ob[i];
        int v = slice[i];
        ob[i] = cur > v ? cur : v;
    }
}

__global__ __launch_bounds__(256)
void traverse_direct(const float* __restrict__ h,
                     const int* __restrict__ edge_index,
                     const int* __restrict__ etype,
                     const int* __restrict__ r_index,
                     int* __restrict__ out, int B, int N, int E) {
    __shared__ unsigned int smask[64];
    if (threadIdx.x < 64) {
        unsigned int m = 0;
        for (int b = 0; b < B; ++b)
            if (r_index[b] == (int)threadIdx.x) m |= (1u << b);
        smask[threadIdx.x] = m;
    }
    __syncthreads();
    const int* __restrict__ src = edge_index;
    const int* __restrict__ dst = edge_index + E;
    int e = blockIdx.x * blockDim.x + threadIdx.x;
    if (e < E) {
        unsigned int ty = (unsigned int)etype[e];
        unsigned int m = (ty < 64u) ? smask[ty] : 0u;
        while (m) {
            int b = __builtin_ctz(m); m &= m - 1;
            float v = h[(size_t)b * N + src[e]];
            atomicMax(out + (size_t)b * N + dst[e], __float_as_int(v));
        }
    }
}

extern "C" void kernel_launch(void* const* d_in, const int* in_sizes, int n_in,
                              void* d_out, int out_size, void* d_ws, size_t ws_size,
                              hipStream_t stream) {
    const float* h          = (const float*)d_in[0];
    const int*   edge_index = (const int*)d_in[1];
    const int*   etype      = (const int*)d_in[2];
    const int*   r_index    = (const int*)d_in[3];

    int B = in_sizes[3];
    int N = in_sizes[0] / B;
    int E = in_sizes[2];
    int nchunk = (N + (1 << CSHIFT) - 1) >> CSHIFT;
    int nbkt = B * nchunk;
    int out_n = out_size;
    int* out_i = (int*)d_out;

    // ws layout (all 64B-aligned): flag line | ovcnt NB lines | store | ovrec
    unsigned int* flag  = (unsigned int*)d_ws;
    unsigned int* ovcnt = flag + 16;
    unsigned int* store = ovcnt + (size_t)NB * 16;
    uint2* ovrec = (uint2*)(store + (size_t)nbkt * NB * 16);
    const size_t need_ws = 64 + (size_t)NB * 64 + (size_t)nbkt * NB * 64
                         + (size_t)NB * OVCAP * 8;

    const bool shape_ok = (N <= (1 << 17)) && (B <= 32) && (nbkt >= 1) &&
                          (nbkt <= MAXNBKT) && (nbkt <= NB) &&
                          (ws_size >= need_ws) && (E >= 4) && (out_n == B * N);

    if (shape_ok) {
        void* args[] = {
            (void*)&edge_index, (void*)&etype, (void*)&r_index, (void*)&h,
            (void*)&out_i, (void*)&flag, (void*)&ovcnt, (void*)&ovrec,
            (void*)&store, (void*)&B, (void*)&N, (void*)&E,
            (void*)&nchunk, (void*)&nbkt, (void*)&out_n
        };
        hipError_t err = hipLaunchCooperativeKernel(
            (const void*)fused_kernel, dim3(NB), dim3(TH), args, 0, stream);
        if (err == hipSuccess) return;
        // fall through to R5 chain if cooperative launch unsupported here
    }

    const int nz = (out_size + 1023) / 1024;
    zero_out_kernel<<<nz, 256, 0, stream>>>(out_i, out_size);

    const size_t need_ws5 = (size_t)nbkt * 512 * 64;
    const bool fast5 = (N <= (1 << 17)) && (B <= 32) && (nbkt >= 1) &&
                       (nbkt <= MAXNBKT) && (ws_size >= need_ws5) && (E >= 4);
    if (fast5) {
        unsigned int* store5 = (unsigned int*)d_ws;
        phase1_kernel<<<512, 512, 0, stream>>>(
            edge_index, etype, r_index, h, out_i, store5, B, N, E, nchunk, nbkt);
        phase2_kernel<<<nbkt, 512, 0, stream>>>(h, store5, N, nchunk, out_i);
    } else {
        traverse_direct<<<(E + 255) / 256, 256, 0, stream>>>(
            h, edge_index, etype, r_index, out_i, B, N, E);
    }
}

// Round 8
// 37.689 us; speedup vs baseline: 8.6113x; 8.6113x over previous
//
#include <hip/hip_runtime.h>

// SymbolicTraversal: out[b, n] = max(0, max_{e: type[e]==r_index[b], dst[e]==n} h[b, src[e]])
//
// R7: two plain dispatches, zero global atomics, out written exactly once.
//   phase1: stream edges, filter via relation->batch bitmask, stage records in
//           per-bucket LDS queues, flush each (bucket,block) as one full 64B segment
//           {count, <=15 records}. Queue overflow -> per-block ws list (no atomics on
//           out, raw count in ovcnt[bid] acts as panic sentinel if > OVCAP).
//   phase2: one block per bucket: zero 32KB LDS slice, apply segments (contiguous),
//           apply overflow lists (parallel, bucket-filtered), panic => re-stream all
//           edges for this bucket (max is idempotent, so double-apply is exact),
//           then plain coalesced store to out (no read-merge, no pre-zero needed).
// Record: ((dst & 8191) << 17) | src  (needs N <= 2^17, guarded).
// Fallback for unsupported shapes/ws: zero + direct atomic kernel.

typedef int v4i __attribute__((ext_vector_type(4)));

#define NB1 512
#define TH1 512
#define TH2 512
#define QCAP 15
#define CSHIFT 13
#define MAXNBKT 256
#define OVCAP 16384

__global__ __launch_bounds__(TH1)
void phase1_kernel(const int* __restrict__ edge_index, // [2][E]
                   const int* __restrict__ etype,      // [E]
                   const int* __restrict__ r_index,    // [B]
                   unsigned int* __restrict__ ovcnt,   // [NB1] raw counts
                   uint2* __restrict__ ovrec,          // [NB1][OVCAP]
                   unsigned int* __restrict__ store,   // [nbkt][NB1][16]
                   int B, int N, int E, int nchunk, int nbkt) {
    __shared__ unsigned int smask[64];
    __shared__ unsigned int lcnt[MAXNBKT];
    __shared__ unsigned int lq[MAXNBKT * QCAP];
    __shared__ unsigned int sov;

    const int t = threadIdx.x;
    const int bid = blockIdx.x;
    if (t < 64) {
        unsigned int m = 0;
        for (int b = 0; b < B; ++b)
            if (r_index[b] == t) m |= (1u << b);
        smask[t] = m;
    }
    for (int i = t; i < nbkt; i += TH1) lcnt[i] = 0;
    if (t == 0) sov = 0;
    __syncthreads();

    const int* __restrict__ src = edge_index;
    const int* __restrict__ dst = edge_index + E;
    const unsigned int cmask = (1u << CSHIFT) - 1u;
    const int nq = E >> 2;

    for (int q = bid * TH1 + t; q < nq; q += NB1 * TH1) {
        v4i tv = __builtin_nontemporal_load(reinterpret_cast<const v4i*>(etype) + q);
        v4i sv = __builtin_nontemporal_load(reinterpret_cast<const v4i*>(src) + q);
        v4i dv = __builtin_nontemporal_load(reinterpret_cast<const v4i*>(dst) + q);
        #pragma unroll
        for (int i = 0; i < 4; ++i) {
            unsigned int ty = (unsigned int)tv[i];
            unsigned int m = (ty < 64u) ? smask[ty] : 0u;
            if (!m) continue;
            unsigned int d = (unsigned int)dv[i];
            unsigned int s = (unsigned int)sv[i];
            unsigned int rec = ((d & cmask) << 17) | s;
            int cb = (int)(d >> CSHIFT);
            do {
                int b = __builtin_ctz(m); m &= m - 1;
                int bkt = b * nchunk + cb;
                unsigned int pos = atomicAdd(&lcnt[bkt], 1u);
                if (pos < QCAP) {
                    lq[bkt * QCAP + pos] = rec;
                } else {
                    unsigned int p2 = atomicAdd(&sov, 1u);
                    if (p2 < OVCAP) {
                        uint2 rr; rr.x = (d << 5) | (unsigned int)b; rr.y = s;
                        ovrec[(size_t)bid * OVCAP + p2] = rr;
                    } // beyond OVCAP: dropped; raw count > OVCAP triggers panic re-stream
                }
            } while (m);
        }
    }
    if (bid == 0) {  // tail edges (E % 4)
        for (int e = (nq << 2) + t; e < E; e += TH1) {
            unsigned int ty = (unsigned int)etype[e];
            unsigned int m = (ty < 64u) ? smask[ty] : 0u;
            unsigned int d = (unsigned int)dst[e];
            unsigned int s = (unsigned int)src[e];
            unsigned int rec = ((d & cmask) << 17) | s;
            int cb = (int)(d >> CSHIFT);
            while (m) {
                int b = __builtin_ctz(m); m &= m - 1;
                int bkt = b * nchunk + cb;
                unsigned int pos = atomicAdd(&lcnt[bkt], 1u);
                if (pos < QCAP) {
                    lq[bkt * QCAP + pos] = rec;
                } else {
                    unsigned int p2 = atomicAdd(&sov, 1u);
                    if (p2 < OVCAP) {
                        uint2 rr; rr.x = (d << 5) | (unsigned int)b; rr.y = s;
                        ovrec[(size_t)bid * OVCAP + p2] = rr;
                    }
                }
            }
        }
    }
    __syncthreads();

    if (t == 0) ovcnt[bid] = sov;  // raw (not clamped): >OVCAP means panic

    // Flush: each bucket -> one full 64B line. 16 lanes/bucket, 4 buckets/wave.
    const int wid = t >> 6, lane = t & 63;
    const int sub = lane >> 4, word = lane & 15;
    for (int k0 = wid * 4; k0 < nbkt; k0 += (TH1 / 64) * 4) {
        int k = k0 + sub;
        if (k < nbkt) {
            unsigned int n = lcnt[k]; if (n > QCAP) n = QCAP;
            unsigned int val = (word == 0) ? n : lq[k * QCAP + (word - 1)];
            store[((size_t)k * NB1 + bid) * 16 + word] = val;
        }
    }
}

__global__ __launch_bounds__(TH2)
void phase2_kernel(const float* __restrict__ h,
                   const unsigned int* __restrict__ store,
                   const unsigned int* __restrict__ ovcnt,
                   const uint2* __restrict__ ovrec,
                   const int* __restrict__ edge_index,
                   const int* __restrict__ etype,
                   const int* __restrict__ r_index,
                   int N, int E, int nchunk,
                   int* __restrict__ out) {
    __shared__ int slice[1 << CSHIFT];  // 32KB
    __shared__ int spanic;

    const int t = threadIdx.x;
    const int k = blockIdx.x;           // bucket
    const int b = k / nchunk;
    const int c = k % nchunk;
    const int csz = 1 << CSHIFT;
    const unsigned int cmask = (1u << CSHIFT) - 1u;

    for (int i = t; i < csz; i += TH2) slice[i] = 0;
    if (t == 0) spanic = 0;
    __syncthreads();

    const unsigned int* __restrict__ base = store + (size_t)k * NB1 * 16;
    const float* __restrict__ hb = h + (size_t)b * N;

    // Apply segments: one per thread, contiguous 64B lines.
    for (int r = t; r < NB1; r += TH2) {
        const unsigned int* __restrict__ seg = base + (size_t)r * 16;
        unsigned int n = seg[0]; if (n > QCAP) n = QCAP;
        for (unsigned int i = 1; i <= n; ++i) {
            unsigned int rec = seg[i];
            int s  = (int)(rec & 0x1FFFFu);
            int ld = (int)(rec >> 17);
            atomicMax(&slice[ld], __float_as_int(hb[s]));
        }
    }

    // Apply overflow lists: thread t owns list t (coalesced count read, tiny lists).
    for (int r = t; r < NB1; r += TH2) {
        unsigned int raw = ovcnt[r];
        if (raw > OVCAP) { atomicOr(&spanic, 1); raw = OVCAP; }
        const uint2* __restrict__ rp = ovrec + (size_t)r * OVCAP;
        for (unsigned int i = 0; i < raw; ++i) {
            uint2 rr = rp[i];
            int bb = (int)(rr.x & 31u);
            unsigned int d = rr.x >> 5;
            if (bb == b && (int)(d >> CSHIFT) == c)
                atomicMax(&slice[d & cmask], __float_as_int(hb[rr.y]));
        }
    }
    __syncthreads();

    if (spanic) {  // ultra-rare: re-stream all edges for this bucket (idempotent max)
        const int rb = r_index[b];
        const int* __restrict__ src = edge_index;
        const int* __restrict__ dst = edge_index + E;
        for (int e = t; e < E; e += TH2) {
            if (etype[e] == rb) {
                unsigned int d = (unsigned int)dst[e];
                if ((int)(d >> CSHIFT) == c)
                    atomicMax(&slice[d & cmask], __float_as_int(hb[src[e]]));
            }
        }
        __syncthreads();
    }

    // Plain coalesced store (out never read; covers clamp floor + empty segments).
    const int d0 = c << CSHIFT;
    int cnt = N - d0; if (cnt > csz) cnt = csz;
    int* __restrict__ ob = out + (size_t)b * N + d0;
    for (int i = t; i < cnt; i += TH2) ob[i] = slice[i];
}

// ===== Fallback for unsupported shapes / tiny ws =====

__global__ __launch_bounds__(256)
void zero_out_kernel(int* __restrict__ out, int n) {
    int i = (blockIdx.x * 256 + threadIdx.x) * 4;
    if (i + 3 < n) {
        v4i z = {0, 0, 0, 0};
        *reinterpret_cast<v4i*>(out + i) = z;
    } else {
        for (int j = i; j < n && j >= 0; ++j) out[j] = 0;
    }
}

__global__ __launch_bounds__(256)
void traverse_direct(const float* __restrict__ h,
                     const int* __restrict__ edge_index,
                     const int* __restrict__ etype,
                     const int* __restrict__ r_index,
                     int* __restrict__ out, int B, int N, int E) {
    __shared__ unsigned int smask[64];
    if (threadIdx.x < 64) {
        unsigned int m = 0;
        for (int b = 0; b < B; ++b)
            if (r_index[b] == (int)threadIdx.x) m |= (1u << b);
        smask[threadIdx.x] = m;
    }
    __syncthreads();
    const int* __restrict__ src = edge_index;
    const int* __restrict__ dst = edge_index + E;
    int e = blockIdx.x * blockDim.x + threadIdx.x;
    if (e < E) {
        unsigned int ty = (unsigned int)etype[e];
        unsigned int m = (ty < 64u) ? smask[ty] : 0u;
        while (m) {
            int b = __builtin_ctz(m); m &= m - 1;
            float v = h[(size_t)b * N + src[e]];
            atomicMax(out + (size_t)b * N + dst[e], __float_as_int(v));
        }
    }
}

extern "C" void kernel_launch(void* const* d_in, const int* in_sizes, int n_in,
                              void* d_out, int out_size, void* d_ws, size_t ws_size,
                              hipStream_t stream) {
    const float* h          = (const float*)d_in[0];
    const int*   edge_index = (const int*)d_in[1];
    const int*   etype      = (const int*)d_in[2];
    const int*   r_index    = (const int*)d_in[3];

    const int B = in_sizes[3];
    const int N = in_sizes[0] / B;
    const int E = in_sizes[2];
    const int nchunk = (N + (1 << CSHIFT) - 1) >> CSHIFT;
    const int nbkt = B * nchunk;
    int* out_i = (int*)d_out;

    // ws layout: ovcnt u32[NB1] (4KB pad) | store [nbkt][NB1][16] u32 | ovrec [NB1][OVCAP] uint2
    unsigned int* ovcnt = (unsigned int*)d_ws;
    unsigned int* store = ovcnt + 1024;
    const size_t store_words = (size_t)(nbkt > 0 ? nbkt : 1) * NB1 * 16;
    uint2* ovrec = (uint2*)(store + store_words);
    const size_t need_ws = 4096 + store_words * 4 + (size_t)NB1 * OVCAP * 8;

    const bool fast = (N <= (1 << 17)) && (B <= 32) && (nbkt >= 1) &&
                      (nbkt <= MAXNBKT) && (ws_size >= need_ws) && (E >= 4) &&
                      (out_size == B * N);
    if (fast) {
        phase1_kernel<<<NB1, TH1, 0, stream>>>(
            edge_index, etype, r_index, ovcnt, ovrec, store,
            B, N, E, nchunk, nbkt);
        phase2_kernel<<<nbkt, TH2, 0, stream>>>(
            h, store, ovcnt, ovrec, edge_index, etype, r_index,
            N, E, nchunk, out_i);
    } else {
        const int nz = (out_size + 1023) / 1024;
        zero_out_kernel<<<nz, 256, 0, stream>>>(out_i, out_size);
        traverse_direct<<<(E + 255) / 256, 256, 0, stream>>>(
            h, edge_index, etype, r_index, out_i, B, N, E);
    }
}

// Round 9
// 32.313 us; speedup vs baseline: 10.0437x; 1.1664x over previous
//
#include <hip/hip_runtime.h>

// SymbolicTraversal: out[b, n] = max(0, max_{e: type[e]==r_index[b], dst[e]==n} h[b, src[e]])
//
// R8: phase2 made wave-shaped.
//   - (segment,word) processing: lane reads word t&15 of segment t>>4 (fully
//     coalesced), count broadcast via __shfl, parallel gathers + LDS atomics.
//   - CSHIFT 12 -> 400 buckets -> phase2 grid 400 blocks (was 208), 16KB slices.
//   phase1 unchanged structurally (LDS queues -> 64B segment flush, no global atomics).
// Record: ((dst & 4095) << 17) | src  (needs N <= 2^17, guarded).
// Overflow: per-block ws list; panic (> OVCAP, never expected) -> phase2 re-streams
// its bucket's edges (max is idempotent). Fallback path for unsupported shapes.

typedef int v4i __attribute__((ext_vector_type(4)));

#define NB1 512
#define TH1 512
#define TH2 512
#define QCAP 15
#define CSHIFT 12
#define MAXNBKT 448
#define OVCAP 16384

__global__ __launch_bounds__(TH1)
void phase1_kernel(const int* __restrict__ edge_index, // [2][E]
                   const int* __restrict__ etype,      // [E]
                   const int* __restrict__ r_index,    // [B]
                   unsigned int* __restrict__ ovcnt,   // [NB1] raw counts
                   uint2* __restrict__ ovrec,          // [NB1][OVCAP]
                   unsigned int* __restrict__ store,   // [nbkt][NB1][16]
                   int B, int N, int E, int nchunk, int nbkt) {
    __shared__ unsigned int smask[64];
    __shared__ unsigned int lcnt[MAXNBKT];
    __shared__ unsigned int lq[MAXNBKT * QCAP];
    __shared__ unsigned int sov;

    const int t = threadIdx.x;
    const int bid = blockIdx.x;
    if (t < 64) {
        unsigned int m = 0;
        for (int b = 0; b < B; ++b)
            if (r_index[b] == t) m |= (1u << b);
        smask[t] = m;
    }
    for (int i = t; i < nbkt; i += TH1) lcnt[i] = 0;
    if (t == 0) sov = 0;
    __syncthreads();

    const int* __restrict__ src = edge_index;
    const int* __restrict__ dst = edge_index + E;
    const unsigned int cmask = (1u << CSHIFT) - 1u;
    const int nq = E >> 2;

    for (int q = bid * TH1 + t; q < nq; q += NB1 * TH1) {
        v4i tv = __builtin_nontemporal_load(reinterpret_cast<const v4i*>(etype) + q);
        v4i sv = __builtin_nontemporal_load(reinterpret_cast<const v4i*>(src) + q);
        v4i dv = __builtin_nontemporal_load(reinterpret_cast<const v4i*>(dst) + q);
        #pragma unroll
        for (int i = 0; i < 4; ++i) {
            unsigned int ty = (unsigned int)tv[i];
            unsigned int m = (ty < 64u) ? smask[ty] : 0u;
            if (!m) continue;
            unsigned int d = (unsigned int)dv[i];
            unsigned int s = (unsigned int)sv[i];
            unsigned int rec = ((d & cmask) << 17) | s;
            int cb = (int)(d >> CSHIFT);
            do {
                int b = __builtin_ctz(m); m &= m - 1;
                int bkt = b * nchunk + cb;
                unsigned int pos = atomicAdd(&lcnt[bkt], 1u);
                if (pos < QCAP) {
                    lq[bkt * QCAP + pos] = rec;
                } else {
                    unsigned int p2 = atomicAdd(&sov, 1u);
                    if (p2 < OVCAP) {
                        uint2 rr; rr.x = (d << 5) | (unsigned int)b; rr.y = s;
                        ovrec[(size_t)bid * OVCAP + p2] = rr;
                    } // beyond OVCAP: dropped; raw count > OVCAP triggers panic re-stream
                }
            } while (m);
        }
    }
    if (bid == 0) {  // tail edges (E % 4)
        for (int e = (nq << 2) + t; e < E; e += TH1) {
            unsigned int ty = (unsigned int)etype[e];
            unsigned int m = (ty < 64u) ? smask[ty] : 0u;
            unsigned int d = (unsigned int)dst[e];
            unsigned int s = (unsigned int)src[e];
            unsigned int rec = ((d & cmask) << 17) | s;
            int cb = (int)(d >> CSHIFT);
            while (m) {
                int b = __builtin_ctz(m); m &= m - 1;
                int bkt = b * nchunk + cb;
                unsigned int pos = atomicAdd(&lcnt[bkt], 1u);
                if (pos < QCAP) {
                    lq[bkt * QCAP + pos] = rec;
                } else {
                    unsigned int p2 = atomicAdd(&sov, 1u);
                    if (p2 < OVCAP) {
                        uint2 rr; rr.x = (d << 5) | (unsigned int)b; rr.y = s;
                        ovrec[(size_t)bid * OVCAP + p2] = rr;
                    }
                }
            }
        }
    }
    __syncthreads();

    if (t == 0) ovcnt[bid] = sov;  // raw (not clamped): >OVCAP means panic

    // Flush: each bucket -> one full 64B line. 16 lanes/bucket, 4 buckets/wave.
    const int wid = t >> 6, lane = t & 63;
    const int sub = lane >> 4, word = lane & 15;
    for (int k0 = wid * 4; k0 < nbkt; k0 += (TH1 / 64) * 4) {
        int k = k0 + sub;
        if (k < nbkt) {
            unsigned int n = lcnt[k]; if (n > QCAP) n = QCAP;
            unsigned int val = (word == 0) ? n : lq[k * QCAP + (word - 1)];
            store[((size_t)k * NB1 + bid) * 16 + word] = val;
        }
    }
}

__global__ __launch_bounds__(TH2)
void phase2_kernel(const float* __restrict__ h,
                   const unsigned int* __restrict__ store,
                   const unsigned int* __restrict__ ovcnt,
                   const uint2* __restrict__ ovrec,
                   const int* __restrict__ edge_index,
                   const int* __restrict__ etype,
                   const int* __restrict__ r_index,
                   int N, int E, int nchunk,
                   int* __restrict__ out) {
    __shared__ int slice[1 << CSHIFT];  // 16KB
    __shared__ int spanic;

    const int t = threadIdx.x;
    const int k = blockIdx.x;           // bucket
    const int b = k / nchunk;
    const int c = k % nchunk;
    const int csz = 1 << CSHIFT;
    const unsigned int cmask = (1u << CSHIFT) - 1u;

    for (int i = t; i < csz; i += TH2) slice[i] = 0;
    if (t == 0) spanic = 0;
    __syncthreads();

    const unsigned int* __restrict__ base = store + (size_t)k * NB1 * 16;
    const float* __restrict__ hb = h + (size_t)b * N;

    // Wave-shaped segment apply: lane reads word (t&15) of segment (t>>4).
    // Coalesced 2KB loads per wave-group; count broadcast via shfl; all active
    // lanes gather + LDS-atomic in parallel (deep MLP).
    const int lane16 = t & 15;
    const int srcLane = (t & 63) & ~15;
    #pragma unroll 2
    for (int pass = 0; pass < NB1 / (TH2 / 16); ++pass) {
        int seg = pass * (TH2 / 16) + (t >> 4);
        unsigned int w = base[(size_t)seg * 16 + lane16];
        unsigned int n = (unsigned int)__shfl((int)w, srcLane, 64);
        if (n > QCAP) n = QCAP;
        if (lane16 >= 1 && (unsigned int)lane16 <= n) {
            int s  = (int)(w & 0x1FFFFu);
            int ld = (int)(w >> 17);
            atomicMax(&slice[ld], __float_as_int(hb[s]));
        }
    }

    // Overflow lists: thread r owns list r (counts ~0 in practice).
    for (int r = t; r < NB1; r += TH2) {
        unsigned int raw = ovcnt[r];
        if (raw > OVCAP) { atomicOr(&spanic, 1); raw = OVCAP; }
        const uint2* __restrict__ rp = ovrec + (size_t)r * OVCAP;
        for (unsigned int i = 0; i < raw; ++i) {
            uint2 rr = rp[i];
            int bb = (int)(rr.x & 31u);
            unsigned int d = rr.x >> 5;
            if (bb == b && (int)(d >> CSHIFT) == c)
                atomicMax(&slice[d & cmask], __float_as_int(hb[rr.y]));
        }
    }
    __syncthreads();

    if (spanic) {  // ultra-rare: re-stream all edges for this bucket (idempotent max)
        const int rb = r_index[b];
        const int* __restrict__ src = edge_index;
        const int* __restrict__ dst = edge_index + E;
        for (int e = t; e < E; e += TH2) {
            if (etype[e] == rb) {
                unsigned int d = (unsigned int)dst[e];
                if ((int)(d >> CSHIFT) == c)
                    atomicMax(&slice[d & cmask], __float_as_int(hb[src[e]]));
            }
        }
        __syncthreads();
    }

    // Plain coalesced store (out never read; covers clamp floor + empty segments).
    const int d0 = c << CSHIFT;
    int cnt = N - d0; if (cnt > csz) cnt = csz;
    int* __restrict__ ob = out + (size_t)b * N + d0;
    for (int i = t; i < cnt; i += TH2) ob[i] = slice[i];
}

// ===== Fallback for unsupported shapes / tiny ws =====

__global__ __launch_bounds__(256)
void zero_out_kernel(int* __restrict__ out, int n) {
    int i = (blockIdx.x * 256 + threadIdx.x) * 4;
    if (i + 3 < n) {
        v4i z = {0, 0, 0, 0};
        *reinterpret_cast<v4i*>(out + i) = z;
    } else {
        for (int j = i; j < n && j >= 0; ++j) out[j] = 0;
    }
}

__global__ __launch_bounds__(256)
void traverse_direct(const float* __restrict__ h,
                     const int* __restrict__ edge_index,
                     const int* __restrict__ etype,
                     const int* __restrict__ r_index,
                     int* __restrict__ out, int B, int N, int E) {
    __shared__ unsigned int smask[64];
    if (threadIdx.x < 64) {
        unsigned int m = 0;
        for (int b = 0; b < B; ++b)
            if (r_index[b] == (int)threadIdx.x) m |= (1u << b);
        smask[threadIdx.x] = m;
    }
    __syncthreads();
    const int* __restrict__ src = edge_index;
    const int* __restrict__ dst = edge_index + E;
    int e = blockIdx.x * blockDim.x + threadIdx.x;
    if (e < E) {
        unsigned int ty = (unsigned int)etype[e];
        unsigned int m = (ty < 64u) ? smask[ty] : 0u;
        while (m) {
            int b = __builtin_ctz(m); m &= m - 1;
            float v = h[(size_t)b * N + src[e]];
            atomicMax(out + (size_t)b * N + dst[e], __float_as_int(v));
        }
    }
}

extern "C" void kernel_launch(void* const* d_in, const int* in_sizes, int n_in,
                              void* d_out, int out_size, void* d_ws, size_t ws_size,
                              hipStream_t stream) {
    const float* h          = (const float*)d_in[0];
    const int*   edge_index = (const int*)d_in[1];
    const int*   etype      = (const int*)d_in[2];
    const int*   r_index    = (const int*)d_in[3];

    const int B = in_sizes[3];
    const int N = in_sizes[0] / B;
    const int E = in_sizes[2];
    const int nchunk = (N + (1 << CSHIFT) - 1) >> CSHIFT;
    const int nbkt = B * nchunk;
    int* out_i = (int*)d_out;

    // ws layout: ovcnt u32[NB1] (4KB pad) | store [nbkt][NB1][16] u32 | ovrec [NB1][OVCAP] uint2
    unsigned int* ovcnt = (unsigned int*)d_ws;
    unsigned int* store = ovcnt + 1024;
    const size_t store_words = (size_t)(nbkt > 0 ? nbkt : 1) * NB1 * 16;
    uint2* ovrec = (uint2*)(store + store_words);
    const size_t need_ws = 4096 + store_words * 4 + (size_t)NB1 * OVCAP * 8;

    const bool fast = (N <= (1 << 17)) && (B <= 32) && (nbkt >= 1) &&
                      (nbkt <= MAXNBKT) && (ws_size >= need_ws) && (E >= 4) &&
                      (out_size == B * N);
    if (fast) {
        phase1_kernel<<<NB1, TH1, 0, stream>>>(
            edge_index, etype, r_index, ovcnt, ovrec, store,
            B, N, E, nchunk, nbkt);
        phase2_kernel<<<nbkt, TH2, 0, stream>>>(
            h, store, ovcnt, ovrec, edge_index, etype, r_index,
            N, E, nchunk, out_i);
    } else {
        const int nz = (out_size + 1023) / 1024;
        zero_out_kernel<<<nz, 256, 0, stream>>>(out_i, out_size);
        traverse_direct<<<(E + 255) / 256, 256, 0, stream>>>(
            h, edge_index, etype, r_index, out_i, B, N, E);
    }
}

// Round 10
// 32.191 us; speedup vs baseline: 10.0820x; 1.0038x over previous
//
#include <hip/hip_runtime.h>

// SymbolicTraversal: out[b, n] = max(0, max_{e: type[e]==r_index[b], dst[e]==n} h[b, src[e]])
//
// R9: occupancy experiment — R8 structure unchanged, TH1/TH2 512 -> 1024.
//   phase1: 512 blocks x 1024 thr (2 blocks/CU, 2048 thr/CU = full) stream edges,
//           filter via relation->batch bitmask, LDS queues -> 64B segment flush.
//   phase2: 400 blocks x 1024 thr, wave-shaped (segment,word) apply, LDS slice max,
//           plain coalesced store.
// Record: ((dst & 4095) << 17) | src  (needs N <= 2^17, guarded).
// Overflow: per-block ws list; panic (> OVCAP) -> phase2 re-streams bucket edges.

typedef int v4i __attribute__((ext_vector_type(4)));

#define NB1 512
#define TH1 1024
#define TH2 1024
#define QCAP 15
#define CSHIFT 12
#define MAXNBKT 448
#define OVCAP 16384

__global__ __launch_bounds__(TH1)
void phase1_kernel(const int* __restrict__ edge_index, // [2][E]
                   const int* __restrict__ etype,      // [E]
                   const int* __restrict__ r_index,    // [B]
                   unsigned int* __restrict__ ovcnt,   // [NB1] raw counts
                   uint2* __restrict__ ovrec,          // [NB1][OVCAP]
                   unsigned int* __restrict__ store,   // [nbkt][NB1][16]
                   int B, int N, int E, int nchunk, int nbkt) {
    __shared__ unsigned int smask[64];
    __shared__ unsigned int lcnt[MAXNBKT];
    __shared__ unsigned int lq[MAXNBKT * QCAP];
    __shared__ unsigned int sov;

    const int t = threadIdx.x;
    const int bid = blockIdx.x;
    if (t < 64) {
        unsigned int m = 0;
        for (int b = 0; b < B; ++b)
            if (r_index[b] == t) m |= (1u << b);
        smask[t] = m;
    }
    for (int i = t; i < nbkt; i += TH1) lcnt[i] = 0;
    if (t == 0) sov = 0;
    __syncthreads();

    const int* __restrict__ src = edge_index;
    const int* __restrict__ dst = edge_index + E;
    const unsigned int cmask = (1u << CSHIFT) - 1u;
    const int nq = E >> 2;

    for (int q = bid * TH1 + t; q < nq; q += NB1 * TH1) {
        v4i tv = __builtin_nontemporal_load(reinterpret_cast<const v4i*>(etype) + q);
        v4i sv = __builtin_nontemporal_load(reinterpret_cast<const v4i*>(src) + q);
        v4i dv = __builtin_nontemporal_load(reinterpret_cast<const v4i*>(dst) + q);
        #pragma unroll
        for (int i = 0; i < 4; ++i) {
            unsigned int ty = (unsigned int)tv[i];
            unsigned int m = (ty < 64u) ? smask[ty] : 0u;
            if (!m) continue;
            unsigned int d = (unsigned int)dv[i];
            unsigned int s = (unsigned int)sv[i];
            unsigned int rec = ((d & cmask) << 17) | s;
            int cb = (int)(d >> CSHIFT);
            do {
                int b = __builtin_ctz(m); m &= m - 1;
                int bkt = b * nchunk + cb;
                unsigned int pos = atomicAdd(&lcnt[bkt], 1u);
                if (pos < QCAP) {
                    lq[bkt * QCAP + pos] = rec;
                } else {
                    unsigned int p2 = atomicAdd(&sov, 1u);
                    if (p2 < OVCAP) {
                        uint2 rr; rr.x = (d << 5) | (unsigned int)b; rr.y = s;
                        ovrec[(size_t)bid * OVCAP + p2] = rr;
                    } // beyond OVCAP: dropped; raw count > OVCAP triggers panic re-stream
                }
            } while (m);
        }
    }
    if (bid == 0) {  // tail edges (E % 4)
        for (int e = (nq << 2) + t; e < E; e += TH1) {
            unsigned int ty = (unsigned int)etype[e];
            unsigned int m = (ty < 64u) ? smask[ty] : 0u;
            unsigned int d = (unsigned int)dst[e];
            unsigned int s = (unsigned int)src[e];
            unsigned int rec = ((d & cmask) << 17) | s;
            int cb = (int)(d >> CSHIFT);
            while (m) {
                int b = __builtin_ctz(m); m &= m - 1;
                int bkt = b * nchunk + cb;
                unsigned int pos = atomicAdd(&lcnt[bkt], 1u);
                if (pos < QCAP) {
                    lq[bkt * QCAP + pos] = rec;
                } else {
                    unsigned int p2 = atomicAdd(&sov, 1u);
                    if (p2 < OVCAP) {
                        uint2 rr; rr.x = (d << 5) | (unsigned int)b; rr.y = s;
                        ovrec[(size_t)bid * OVCAP + p2] = rr;
                    }
                }
            }
        }
    }
    __syncthreads();

    if (t == 0) ovcnt[bid] = sov;  // raw (not clamped): >OVCAP means panic

    // Flush: each bucket -> one full 64B line. 16 lanes/bucket, 4 buckets/wave.
    const int wid = t >> 6, lane = t & 63;
    const int sub = lane >> 4, word = lane & 15;
    for (int k0 = wid * 4; k0 < nbkt; k0 += (TH1 / 64) * 4) {
        int k = k0 + sub;
        if (k < nbkt) {
            unsigned int n = lcnt[k]; if (n > QCAP) n = QCAP;
            unsigned int val = (word == 0) ? n : lq[k * QCAP + (word - 1)];
            store[((size_t)k * NB1 + bid) * 16 + word] = val;
        }
    }
}

__global__ __launch_bounds__(TH2)
void phase2_kernel(const float* __restrict__ h,
                   const unsigned int* __restrict__ store,
                   const unsigned int* __restrict__ ovcnt,
                   const uint2* __restrict__ ovrec,
                   const int* __restrict__ edge_index,
                   const int* __restrict__ etype,
                   const int* __restrict__ r_index,
                   int N, int E, int nchunk,
                   int* __restrict__ out) {
    __shared__ int slice[1 << CSHIFT];  // 16KB
    __shared__ int spanic;

    const int t = threadIdx.x;
    const int k = blockIdx.x;           // bucket
    const int b = k / nchunk;
    const int c = k % nchunk;
    const int csz = 1 << CSHIFT;
    const unsigned int cmask = (1u << CSHIFT) - 1u;

    for (int i = t; i < csz; i += TH2) slice[i] = 0;
    if (t == 0) spanic = 0;
    __syncthreads();

    const unsigned int* __restrict__ base = store + (size_t)k * NB1 * 16;
    const float* __restrict__ hb = h + (size_t)b * N;

    // Wave-shaped segment apply: lane reads word (t&15) of segment (t>>4).
    // Coalesced loads; count broadcast via shfl; active lanes gather + LDS-atomic
    // in parallel (deep MLP).
    const int lane16 = t & 15;
    const int srcLane = (t & 63) & ~15;
    #pragma unroll 2
    for (int pass = 0; pass < NB1 / (TH2 / 16); ++pass) {
        int seg = pass * (TH2 / 16) + (t >> 4);
        unsigned int w = base[(size_t)seg * 16 + lane16];
        unsigned int n = (unsigned int)__shfl((int)w, srcLane, 64);
        if (n > QCAP) n = QCAP;
        if (lane16 >= 1 && (unsigned int)lane16 <= n) {
            int s  = (int)(w & 0x1FFFFu);
            int ld = (int)(w >> 17);
            atomicMax(&slice[ld], __float_as_int(hb[s]));
        }
    }

    // Overflow lists: thread r owns list r (counts ~0 in practice).
    for (int r = t; r < NB1; r += TH2) {
        unsigned int raw = ovcnt[r];
        if (raw > OVCAP) { atomicOr(&spanic, 1); raw = OVCAP; }
        const uint2* __restrict__ rp = ovrec + (size_t)r * OVCAP;
        for (unsigned int i = 0; i < raw; ++i) {
            uint2 rr = rp[i];
            int bb = (int)(rr.x & 31u);
            unsigned int d = rr.x >> 5;
            if (bb == b && (int)(d >> CSHIFT) == c)
                atomicMax(&slice[d & cmask], __float_as_int(hb[rr.y]));
        }
    }
    __syncthreads();

    if (spanic) {  // ultra-rare: re-stream all edges for this bucket (idempotent max)
        const int rb = r_index[b];
        const int* __restrict__ src = edge_index;
        const int* __restrict__ dst = edge_index + E;
        for (int e = t; e < E; e += TH2) {
            if (etype[e] == rb) {
                unsigned int d = (unsigned int)dst[e];
                if ((int)(d >> CSHIFT) == c)
                    atomicMax(&slice[d & cmask], __float_as_int(hb[src[e]]));
            }
        }
        __syncthreads();
    }

    // Plain coalesced store (out never read; covers clamp floor + empty segments).
    const int d0 = c << CSHIFT;
    int cnt = N - d0; if (cnt > csz) cnt = csz;
    int* __restrict__ ob = out + (size_t)b * N + d0;
    for (int i = t; i < cnt; i += TH2) ob[i] = slice[i];
}

// ===== Fallback for unsupported shapes / tiny ws =====

__global__ __launch_bounds__(256)
void zero_out_kernel(int* __restrict__ out, int n) {
    int i = (blockIdx.x * 256 + threadIdx.x) * 4;
    if (i + 3 < n) {
        v4i z = {0, 0, 0, 0};
        *reinterpret_cast<v4i*>(out + i) = z;
    } else {
        for (int j = i; j < n && j >= 0; ++j) out[j] = 0;
    }
}

__global__ __launch_bounds__(256)
void traverse_direct(const float* __restrict__ h,
                     const int* __restrict__ edge_index,
                     const int* __restrict__ etype,
                     const int* __restrict__ r_index,
                     int* __restrict__ out, int B, int N, int E) {
    __shared__ unsigned int smask[64];
    if (threadIdx.x < 64) {
        unsigned int m = 0;
        for (int b = 0; b < B; ++b)
            if (r_index[b] == (int)threadIdx.x) m |= (1u << b);
        smask[threadIdx.x] = m;
    }
    __syncthreads();
    const int* __restrict__ src = edge_index;
    const int* __restrict__ dst = edge_index + E;
    int e = blockIdx.x * blockDim.x + threadIdx.x;
    if (e < E) {
        unsigned int ty = (unsigned int)etype[e];
        unsigned int m = (ty < 64u) ? smask[ty] : 0u;
        while (m) {
            int b = __builtin_ctz(m); m &= m - 1;
            float v = h[(size_t)b * N + src[e]];
            atomicMax(out + (size_t)b * N + dst[e], __float_as_int(v));
        }
    }
}

extern "C" void kernel_launch(void* const* d_in, const int* in_sizes, int n_in,
                              void* d_out, int out_size, void* d_ws, size_t ws_size,
                              hipStream_t stream) {
    const float* h          = (const float*)d_in[0];
    const int*   edge_index = (const int*)d_in[1];
    const int*   etype      = (const int*)d_in[2];
    const int*   r_index    = (const int*)d_in[3];

    const int B = in_sizes[3];
    const int N = in_sizes[0] / B;
    const int E = in_sizes[2];
    const int nchunk = (N + (1 << CSHIFT) - 1) >> CSHIFT;
    const int nbkt = B * nchunk;
    int* out_i = (int*)d_out;

    // ws layout: ovcnt u32[NB1] (4KB pad) | store [nbkt][NB1][16] u32 | ovrec [NB1][OVCAP] uint2
    unsigned int* ovcnt = (unsigned int*)d_ws;
    unsigned int* store = ovcnt + 1024;
    const size_t store_words = (size_t)(nbkt > 0 ? nbkt : 1) * NB1 * 16;
    uint2* ovrec = (uint2*)(store + store_words);
    const size_t need_ws = 4096 + store_words * 4 + (size_t)NB1 * OVCAP * 8;

    const bool fast = (N <= (1 << 17)) && (B <= 32) && (nbkt >= 1) &&
                      (nbkt <= MAXNBKT) && (ws_size >= need_ws) && (E >= 4) &&
                      (out_size == B * N);
    if (fast) {
        phase1_kernel<<<NB1, TH1, 0, stream>>>(
            edge_index, etype, r_index, ovcnt, ovrec, store,
            B, N, E, nchunk, nbkt);
        phase2_kernel<<<nbkt, TH2, 0, stream>>>(
            h, store, ovcnt, ovrec, edge_index, etype, r_index,
            N, E, nchunk, out_i);
    } else {
        const int nz = (out_size + 1023) / 1024;
        zero_out_kernel<<<nz, 256, 0, stream>>>(out_i, out_size);
        traverse_direct<<<(E + 255) / 256, 256, 0, stream>>>(
            h, edge_index, etype, r_index, out_i, B, N, E);
    }
}